// Round 3
// baseline (564799.268 us; speedup 1.0000x reference)
//
#include <hip/hip_runtime.h>
#include <hip/hip_cooperative_groups.h>
#include <cstddef>

namespace cg = cooperative_groups;

#define B_   32
#define TE_  512
#define TD_  512
#define NM_  80
#define PRE_ 256
#define EH_  512
#define AH_  1024
#define AD_  128

__device__ __forceinline__ float sigf(float x) { return 1.0f / (1.0f + expf(-x)); }

// ---------------- prologue: weight packing for LDS/VGPR-resident scheme ----------------
// WAL/WDL: [blk][k<896][32 rows]  (rows are block-local gate-rows rp = blk*32+r, r=j*4+g order)
// WAR/WDR: [blk][i][tid 512][2]   thread tid=(rp<<5)|ks owns rows {2rp,2rp+1}, k = 896+ks+32i
__global__ __launch_bounds__(256) void k_pack_lstm(
    const float* __restrict__ awih, const float* __restrict__ awhh,
    const float* __restrict__ dwih, const float* __restrict__ dwhh,
    float* __restrict__ wal, float* __restrict__ war,
    float* __restrict__ wdl, float* __restrict__ wdr)
{
  long gid = blockIdx.x * 256L + threadIdx.x;
  const long NL = 3670016;  // 128*896*32
  if (gid < NL) {
    int blk = (int)(gid / 28672), rem = (int)(gid % 28672);
    int k = rem >> 5, r = rem & 31;
    int rp = blk * 32 + r, row = (rp & 3) * 1024 + (rp >> 2);
    wal[gid] = (k < 768) ? awih[(size_t)row * 768 + k] : awhh[(size_t)row * 1024 + k - 768];
  } else if (gid < 2 * NL) {
    long g = gid - NL;
    int blk = (int)(g / 28672), rem = (int)(g % 28672);
    int i = rem >> 10, tc = (rem >> 1) & 511, c = rem & 1;
    int rp = blk * 32 + 2 * (tc >> 5) + c, row = (rp & 3) * 1024 + (rp >> 2);
    int k = 896 + (tc & 31) + 32 * i;   // 896..1791 -> always whh region (k-768 in [128,1024))
    war[g] = awhh[(size_t)row * 1024 + k - 768];
  } else if (gid < 3 * NL) {
    long g = gid - 2 * NL;
    int blk = (int)(g / 28672), rem = (int)(g % 28672);
    int k = rem >> 5, r = rem & 31;
    int rp = blk * 32 + r, row = (rp & 3) * 1024 + (rp >> 2);
    wdl[g] = (k < 1536) ? dwih[(size_t)row * 1536 + k] : dwhh[(size_t)row * 1024 + k - 1536];
  } else {
    long g = gid - 3 * NL;  // < 128*52*1024 = 6815744
    int blk = (int)(g / 53248), rem = (int)(g % 53248);
    int i = rem >> 10, tc = (rem >> 1) & 511, c = rem & 1;
    int rp = blk * 32 + 2 * (tc >> 5) + c, row = (rp & 3) * 1024 + (rp >> 2);
    int k = 896 + (tc & 31) + 32 * i;   // 896..2559
    wdr[g] = (k < 1536) ? dwih[(size_t)row * 1536 + k] : dwhh[(size_t)row * 1024 + k - 1536];
  }
}

__global__ __launch_bounds__(256) void k_pack_small(
    const float* __restrict__ w1, const float* __restrict__ w2,
    const float* __restrict__ mw, const float* __restrict__ pw,
    const float* __restrict__ abih, const float* __restrict__ abhh,
    const float* __restrict__ dbih, const float* __restrict__ dbhh,
    const float* __restrict__ lw, const float* __restrict__ cw,
    float* __restrict__ w1t, float* __restrict__ w2t, float* __restrict__ mt,
    float* __restrict__ pjt, float* __restrict__ ba, float* __restrict__ bd,
    float* __restrict__ lc)
{
  int gid = blockIdx.x * 256 + threadIdx.x;
  if (gid < 20480) { int k = gid / 256, j = gid % 256; w1t[gid] = w1[j * 80 + k]; return; }
  gid -= 20480;
  if (gid < 65536) { int k = gid / 256, j = gid % 256; w2t[gid] = w2[j * 256 + k]; return; }
  gid -= 65536;
  if (gid < 65536) { int e = gid / 128, d = gid % 128; mt[gid] = mw[d * 512 + e]; return; }
  gid -= 65536;
  if (gid < 122880) { int k = gid / 80, m = gid % 80; pjt[gid] = pw[m * 1536 + k]; return; }
  gid -= 122880;
  if (gid < 4096) { int j = gid >> 2, g = gid & 3, row = g * 1024 + j; ba[gid] = abih[row] + abhh[row]; return; }
  gid -= 4096;
  if (gid < 4096) { int j = gid >> 2, g = gid & 3, row = g * 1024 + j; bd[gid] = dbih[row] + dbhh[row]; return; }
  gid -= 4096;
  if (gid < 7936) {
    int c = gid / (31 * 128), rem = gid % (31 * 128);
    int kk = rem / 128, d = rem % 128;
    float s = 0.f;
    for (int f = 0; f < 32; ++f) s += lw[d * 32 + f] * cw[(f * 2 + c) * 31 + kk];
    lc[gid] = s;
  }
}

// ---------------- prologue: prenet (unchanged, verified) ----------------
__global__ __launch_bounds__(256) void k_prenet(
    const float* __restrict__ targets, const float* __restrict__ w1t,
    const float* __restrict__ b1, const float* __restrict__ w2t,
    const float* __restrict__ b2, float* __restrict__ pn)
{
  int t = blockIdx.x, tid = threadIdx.x;
  __shared__ float X[32][80];
  __shared__ float h1[256][33];
  for (int i = tid; i < 2560; i += 256) {
    int b = i / 80, m = i % 80;
    X[b][m] = (t == 0) ? 0.f : targets[((size_t)b * TD_ + (t - 1)) * NM_ + m];
  }
  __syncthreads();
  int j = tid;
  float bj = b1[j];
  for (int bt = 0; bt < 4; ++bt) {
    float acc[8];
#pragma unroll
    for (int i = 0; i < 8; ++i) acc[i] = bj;
    for (int k = 0; k < 80; ++k) {
      float w = w1t[k * 256 + j];
#pragma unroll
      for (int i = 0; i < 8; ++i) acc[i] += w * X[bt * 8 + i][k];
    }
#pragma unroll
    for (int i = 0; i < 8; ++i) h1[j][bt * 8 + i] = fmaxf(acc[i], 0.f);
  }
  __syncthreads();
  float cj = b2[j];
  float* out = pn + (size_t)t * PRE_ * B_;
  for (int bt = 0; bt < 4; ++bt) {
    float acc[8];
#pragma unroll
    for (int i = 0; i < 8; ++i) acc[i] = cj;
    for (int k = 0; k < 256; ++k) {
      float w = w2t[k * 256 + j];
#pragma unroll
      for (int i = 0; i < 8; ++i) acc[i] += w * h1[k][bt * 8 + i];
    }
#pragma unroll
    for (int i = 0; i < 8; ++i) out[j * 32 + bt * 8 + i] = fmaxf(acc[i], 0.f);
  }
}

// ---------------- prologue: processed_enc (unchanged, verified) ----------------
__global__ __launch_bounds__(256) void k_penc(
    const float* __restrict__ enc, const float* __restrict__ mt,
    float* __restrict__ penc)
{
  int t = blockIdx.x, tid = threadIdx.x;
  __shared__ float encL[32][256];
  __shared__ float red[128][8][2];
  int d = tid & 127, s = tid >> 7;
  float acc[4][8];
#pragma unroll
  for (int bt = 0; bt < 4; ++bt)
#pragma unroll
    for (int i = 0; i < 8; ++i) acc[bt][i] = 0.f;
  for (int eh = 0; eh < 2; ++eh) {
    for (int i = tid; i < 8192; i += 256) {
      int b = i >> 8, e = i & 255;
      encL[b][e] = enc[((size_t)b * TE_ + t) * EH_ + eh * 256 + e];
    }
    __syncthreads();
    for (int bt = 0; bt < 4; ++bt) {
      for (int el = s * 128; el < s * 128 + 128; ++el) {
        float w = mt[(eh * 256 + el) * 128 + d];
#pragma unroll
        for (int i = 0; i < 8; ++i) acc[bt][i] += w * encL[bt * 8 + i][el];
      }
    }
    __syncthreads();
  }
  for (int bt = 0; bt < 4; ++bt) {
#pragma unroll
    for (int i = 0; i < 8; ++i) red[d][i][s] = acc[bt][i];
    __syncthreads();
    if (s == 0) {
#pragma unroll
      for (int i = 0; i < 8; ++i)
        penc[((size_t)t * AD_ + d) * 32 + bt * 8 + i] = red[d][i][0] + red[d][i][1];
    }
    __syncthreads();
  }
}

// ---------------- persistent step kernel ----------------
struct KP {
  const float* wal; const float* war; const float* wdl; const float* wdr;
  const float* pn; const float* penc;
  const float* qw;   const float* ww;   const float* pjt; const float* pjb;
  const float* lc;   const float* ba;   const float* bd;  const float* enc;
  float* ah; float* ac; float* dh; float* dc; float* ctx2; float* aw; float* aws;
  float* aht; float* enp; float* mel; float* align;
};

// GEMM over K in chunks of 224; weights: k<896 from LDS (Wl), k>=896 from VGPRs (wr).
// Thread: rp = tid>>5 (rows 2rp,2rp+1), ks = tid&31 (k == ks mod 32). acc: 2 rows x 32 b.
template<int NCH, int KTOT, int T1, int T2>
__device__ __forceinline__ void lstm_gemm_run(
    const float* __restrict__ xp0, const float* __restrict__ xp1,
    const float* __restrict__ xp2,
    const float* __restrict__ Wl, float* __restrict__ XC,
    const float2* __restrict__ wr,
    float* acc0, float* acc1, int tid, int ks, int r0)
{
  float2 st[7];
  // prefetch chunk 0 into registers
#pragma unroll
  for (int i = 0; i < 7; ++i) {
    int fidx = i * 512 + tid;
    int k = fidx >> 4;
    const float* src = (k < T1) ? xp0 + (size_t)k * 32
                     : (k < T2) ? xp1 + (size_t)(k - T1) * 32
                                : xp2 + (size_t)(k - T2) * 32;
    st[i] = *(const float2*)(src + (fidx & 15) * 2);
  }
#pragma unroll
  for (int c = 0; c < NCH; ++c) {
    __syncthreads();   // previous chunk fully consumed
#pragma unroll
    for (int i = 0; i < 7; ++i) {
      int fidx = i * 512 + tid;
      *(float2*)&XC[(fidx >> 4) * 34 + (fidx & 15) * 2] = st[i];
    }
    __syncthreads();
    if (c + 1 < NCH) {
#pragma unroll
      for (int i = 0; i < 7; ++i) {
        int fidx = i * 512 + tid;
        int k = (c + 1) * 224 + (fidx >> 4);
        if (k < KTOT) {
          const float* src = (k < T1) ? xp0 + (size_t)k * 32
                           : (k < T2) ? xp1 + (size_t)(k - T1) * 32
                                      : xp2 + (size_t)(k - T2) * 32;
          st[i] = *(const float2*)(src + (fidx & 15) * 2);
        }
      }
    }
    const int kmax = (c == NCH - 1) ? (KTOT - 224 * (NCH - 1)) : 224;
#pragma unroll
    for (int i = 0; i < 7; ++i) {
      if (i * 32 < kmax) {
        int kl = ks + 32 * i;
        float2 w;
        if (c < 4) w = *(const float2*)&Wl[(size_t)(c * 224 + kl) * 34 + r0];
        else       w = wr[7 * (c - 4) + i];
#pragma unroll
        for (int bq = 0; bq < 16; ++bq) {
          float2 xv = *(const float2*)&XC[kl * 34 + bq * 2];
          acc0[bq * 2 + 0] += w.x * xv.x; acc0[bq * 2 + 1] += w.x * xv.y;
          acc1[bq * 2 + 0] += w.y * xv.x; acc1[bq * 2 + 1] += w.y * xv.y;
        }
      }
    }
  }
}

__device__ __forceinline__ void lstm_finish(
    float* acc0, float* acc1, float* __restrict__ GT,
    const float* __restrict__ bias, float* __restrict__ cst,
    float* __restrict__ hout, float* __restrict__ aht,
    int rp0, int tid, int ks, int rp)
{
  // butterfly reduce across the 32 ks-lanes (within each half-wave)
#pragma unroll
  for (int m = 1; m <= 16; m <<= 1) {
#pragma unroll
    for (int b = 0; b < 32; ++b) {
      acc0[b] += __shfl_xor(acc0[b], m);
      acc1[b] += __shfl_xor(acc1[b], m);
    }
  }
  if (ks == 0) {
    float* g0 = GT + (tid >> 6) * 128 + (rp & 1) * 64;
#pragma unroll
    for (int b = 0; b < 32; ++b) { g0[b] = acc0[b]; g0[32 + b] = acc1[b]; }
  }
  __syncthreads();
  if (tid < 256) {
    int w2 = tid >> 5, b = tid & 31;
    const float* g = GT + w2 * 128;
    float gi = g[b]      + bias[rp0 + w2 * 4 + 0];
    float gf = g[32 + b] + bias[rp0 + w2 * 4 + 1];
    float gg = g[64 + b] + bias[rp0 + w2 * 4 + 2];
    float go = g[96 + b] + bias[rp0 + w2 * 4 + 3];
    int j = (rp0 >> 2) + w2;
    float c0 = cst[j * 32 + b];
    float c2 = sigf(gf) * c0 + sigf(gi) * tanhf(gg);
    float h2 = sigf(go) * tanhf(c2);
    cst[j * 32 + b] = c2;
    hout[j * 32 + b] = h2;
    if (aht) aht[(size_t)b * 1024 + j] = h2;
  }
}

__device__ __forceinline__ void mel_block(
    const float* __restrict__ dhp, const float* __restrict__ ctp,
    const float* __restrict__ pjt, const float* __restrict__ pjb,
    float* __restrict__ mel, int bb, int tt, float* S, int tid)
{
  float* xo = S + 1536;
  float* ro = S + 3072;
  for (int i = tid; i < 1536; i += 512)
    xo[i] = (i < 1024) ? dhp[i * 32 + bb] : ctp[(i - 1024) * 32 + bb];
  __syncthreads();
  if (tid < 480) {
    int m = tid % 80, k2 = tid / 80;
    float a2 = 0.f;
    for (int k = k2 * 256; k < k2 * 256 + 256; ++k) a2 += pjt[k * 80 + m] * xo[k];
    ro[m * 8 + k2] = a2;
  }
  __syncthreads();
  if (tid < 80) {
    float s3 = pjb[tid];
#pragma unroll
    for (int k = 0; k < 6; ++k) s3 += ro[tid * 8 + k];
    mel[((size_t)bb * TD_ + tt) * NM_ + tid] = s3;
  }
}

__global__ __launch_bounds__(512, 2) void k_step(KP p)
{
  cg::grid_group grid = cg::this_grid();
  extern __shared__ float LDSF[];        // 39104 floats = 156416 B
  float* Wl = LDSF;                      // [896][34] = 30464
  float* XC = LDSF + 30464;              // [224][34] = 7616  (PB/PC scratch aliases here)
  float* GT = LDSF + 38080;              // [8 waves][4 gates][32 b] = 1024

  const int blk = blockIdx.x, tid = threadIdx.x;
  const int ks = tid & 31, rp = tid >> 5, r0 = 2 * rp;
  const bool isA = blk < 128;

  // ---- one-time: load persistent weights into LDS + VGPRs ----
  {
    const float* wlsrc = isA ? p.wal + (size_t)blk * 28672
                             : p.wdl + (size_t)(blk - 128) * 28672;
    for (int i2 = tid; i2 < 896 * 16; i2 += 512) {
      int k = i2 >> 4, rr = (i2 & 15) * 2;
      *(float2*)&Wl[(size_t)k * 34 + rr] = *(const float2*)&wlsrc[(size_t)k * 32 + rr];
    }
  }
  float2 wr[52];
  if (isA) {
    const float* s = p.war + (size_t)blk * 28672;
#pragma unroll
    for (int i = 0; i < 28; ++i) wr[i] = *(const float2*)&s[(size_t)(i * 512 + tid) * 2];
  } else {
    const float* s = p.wdr + (size_t)(blk - 128) * 53248;
#pragma unroll
    for (int i = 0; i < 52; ++i) wr[i] = *(const float2*)&s[(size_t)(i * 512 + tid) * 2];
  }
  __syncthreads();

  for (int t = 0; t < TD_; ++t) {
    const int pc = t & 1, pp = pc ^ 1;
    // ---- PA: lstm_a(t) [blocks 0..127] || lstm_d(t-1) [blocks 128..255] ----
    if (isA) {
      float acc0[32] = {}, acc1[32] = {};
      lstm_gemm_run<8, 1792, 256, 768>(
          p.pn + (size_t)t * 8192, p.ctx2 + pp * 16384, p.ah + pp * 32768,
          Wl, XC, wr, acc0, acc1, tid, ks, r0);
      lstm_finish(acc0, acc1, GT, p.ba, p.ac, p.ah + pc * 32768, p.aht,
                  blk * 32, tid, ks, rp);
    } else if (t > 0) {
      float acc0[32] = {}, acc1[32] = {};
      lstm_gemm_run<12, 2560, 1024, 1536>(
          p.ah + pp * 32768, p.ctx2 + pp * 16384, p.dh + pc * 32768,
          Wl, XC, wr, acc0, acc1, tid, ks, r0);
      lstm_finish(acc0, acc1, GT, p.bd, p.dc, p.dh + pp * 32768, nullptr,
                  (blk - 128) * 32, tid, ks, rp);
    }
    grid.sync();
    // ---- PB: q-slice + location conv + energies partials (all 256 blocks) ----
    {
      int tc = blk >> 3, ds = blk & 7;
      int t0 = tc * 16, d0 = ds * 16;
      float* win = XC;           // 2944
      float* lcs = XC + 2944;    // 992
      float* qs  = XC + 3936;    // 512
      float* wws = XC + 4448;    // 16
      for (int i = tid; i < 2944; i += 512) {
        int c = i / 1472, r = (i >> 5) % 46, bb = i & 31;
        int tg = t0 - 15 + r;
        float v = 0.f;
        if (tg >= 0 && tg < 512) v = (c ? p.aws : p.aw)[tg * 32 + bb];
        win[i] = v;
      }
      for (int i = tid; i < 992; i += 512) {
        int c = i / 496, kk = (i >> 4) % 31, dl = i & 15;
        lcs[i] = p.lc[(c * 31 + kk) * 128 + d0 + dl];
      }
      if (tid < 16) wws[tid] = p.ww[d0 + tid];
      {
        int dl = tid & 15, bb = tid >> 4;
        const float* qrow = p.qw + (size_t)(d0 + dl) * 1024;
        const float* arow = p.aht + (size_t)bb * 1024;
        float acc = 0.f;
#pragma unroll 4
        for (int k = 0; k < 1024; k += 4) {
          float4 qv = *(const float4*)(qrow + k);
          float4 av = *(const float4*)(arow + k);
          acc += qv.x * av.x + qv.y * av.y + qv.z * av.z + qv.w * av.w;
        }
        qs[dl * 32 + bb] = acc;
      }
      __syncthreads();
      {
        int bb = tid & 31, th = tid >> 5;
        int tt = t0 + th;
        float pa[16];
#pragma unroll
        for (int i = 0; i < 16; ++i) pa[i] = 0.f;
        for (int c = 0; c < 2; ++c) {
          for (int kk = 0; kk < 31; ++kk) {
            float wv = win[c * 1472 + (th + kk) * 32 + bb];
            const float4* lr = (const float4*)(lcs + c * 496 + kk * 16);
            float4 l0 = lr[0], l1 = lr[1], l2 = lr[2], l3 = lr[3];
            pa[0]  += l0.x * wv; pa[1]  += l0.y * wv; pa[2]  += l0.z * wv; pa[3]  += l0.w * wv;
            pa[4]  += l1.x * wv; pa[5]  += l1.y * wv; pa[6]  += l1.z * wv; pa[7]  += l1.w * wv;
            pa[8]  += l2.x * wv; pa[9]  += l2.y * wv; pa[10] += l2.z * wv; pa[11] += l2.w * wv;
            pa[12] += l3.x * wv; pa[13] += l3.y * wv; pa[14] += l3.z * wv; pa[15] += l3.w * wv;
          }
        }
        float ep = 0.f;
#pragma unroll
        for (int dl = 0; dl < 16; ++dl) {
          float v = qs[dl * 32 + bb] + p.penc[((size_t)tt * 128 + d0 + dl) * 32 + bb] + pa[dl];
          ep += wws[dl] * tanhf(v);
        }
        p.enp[(size_t)bb * 4096 + tt * 8 + ds] = ep;
      }
    }
    grid.sync();
    // ---- PC: softmax + ctx (+aw/aws/align, +mel(t-1)) ----
    {
      int bb = blk >> 3, et = blk & 7;
      float* Sr  = XC;           // 512
      float* awL = XC + 512;     // 512
      float* cr  = XC + 1024;    // 512
      const float4* ep4 = (const float4*)(p.enp + (size_t)bb * 4096 + tid * 8);
      float4 u0 = ep4[0], u1 = ep4[1];
      float e = u0.x + u0.y + u0.z + u0.w + u1.x + u1.y + u1.z + u1.w;
      Sr[tid] = e; __syncthreads();
      for (int off = 256; off; off >>= 1) {
        if (tid < off) Sr[tid] = fmaxf(Sr[tid], Sr[tid + off]);
        __syncthreads();
      }
      float mx = Sr[0]; __syncthreads();
      float x = expf(e - mx);
      Sr[tid] = x; __syncthreads();
      for (int off = 256; off; off >>= 1) {
        if (tid < off) Sr[tid] += Sr[tid + off];
        __syncthreads();
      }
      float a = x * (1.f / Sr[0]);
      awL[tid] = a;
      __syncthreads();
      int el = tid & 63, ts = tid >> 6;
      const float* eb = p.enc + (size_t)bb * 262144 + (size_t)ts * 64 * 512 + et * 64 + el;
      float acc = 0.f;
      for (int i = 0; i < 64; ++i) acc += awL[ts * 64 + i] * eb[(size_t)i * 512];
      cr[ts * 64 + el] = acc;
      __syncthreads();
      if (tid < 64) {
        float s2 = 0.f;
#pragma unroll
        for (int k = 0; k < 8; ++k) s2 += cr[k * 64 + tid];
        p.ctx2[pc * 16384 + (et * 64 + tid) * 32 + bb] = s2;
      }
      if (et == 0) {
        p.aw[tid * 32 + bb] = a;
        p.aws[tid * 32 + bb] += a;
        p.align[((size_t)bb * TD_ + t) * TE_ + tid] = a;
      }
      if (et == 1 && t > 0) {
        mel_block(p.dh + pp * 32768, p.ctx2 + pp * 16384, p.pjt, p.pjb,
                  p.mel, bb, t - 1, XC, tid);
      }
    }
    grid.sync();
  }
  // ---- epilogue: lstm_d(511), then mel(511). t==512 -> pc=0, pp=1 ----
  if (!isA) {
    float acc0[32] = {}, acc1[32] = {};
    lstm_gemm_run<12, 2560, 1024, 1536>(
        p.ah + 32768, p.ctx2 + 16384, p.dh + 0,
        Wl, XC, wr, acc0, acc1, tid, ks, r0);
    lstm_finish(acc0, acc1, GT, p.bd, p.dc, p.dh + 32768, nullptr,
                (blk - 128) * 32, tid, ks, rp);
  }
  grid.sync();
  if (blk < 32) {
    mel_block(p.dh + 32768, p.ctx2 + 16384, p.pjt, p.pjb, p.mel, blk, 511, XC, tid);
  }
}

extern "C" void kernel_launch(void* const* d_in, const int* in_sizes, int n_in,
                              void* d_out, int out_size, void* d_ws, size_t ws_size,
                              hipStream_t stream)
{
  const float* enc     = (const float*)d_in[0];
  const float* targets = (const float*)d_in[1];
  const float* pw1  = (const float*)d_in[2];
  const float* pb1  = (const float*)d_in[3];
  const float* pw2  = (const float*)d_in[4];
  const float* pb2  = (const float*)d_in[5];
  const float* mw   = (const float*)d_in[6];
  const float* qw   = (const float*)d_in[7];
  const float* www  = (const float*)d_in[8];
  const float* lw   = (const float*)d_in[9];
  const float* cw   = (const float*)d_in[10];
  const float* awih = (const float*)d_in[11];
  const float* awhh = (const float*)d_in[12];
  const float* abih = (const float*)d_in[13];
  const float* abhh = (const float*)d_in[14];
  const float* dwih = (const float*)d_in[15];
  const float* dwhh = (const float*)d_in[16];
  const float* dbih = (const float*)d_in[17];
  const float* dbhh = (const float*)d_in[18];
  const float* pjw  = (const float*)d_in[19];
  const float* pjb  = (const float*)d_in[20];

  float* ws = (float*)d_ws;
  float* WAL  = ws;                        // 3,670,016
  float* WAR  = WAL + 3670016;             // 3,670,016
  float* WDL  = WAR + 3670016;             // 3,670,016
  float* WDR  = WDL + 3670016;             // 6,815,744
  float* PN   = WDR + 6815744;             // 4,194,304
  float* PENC = PN + 4194304;              // 2,097,152
  float* W1T  = PENC + 2097152;            // 20,480 (prologue-only; ENP aliases)
  float* W2T  = W1T + 20480;               // 65,536
  float* MT   = W2T + 65536;               // 65,536
  float* PJT  = MT + 65536;                // 122,880
  float* LC   = PJT + 122880;              // 7,936
  float* BA   = LC + 7936;                 // 4,096
  float* BD   = BA + 4096;                 // 4,096
  float* STATE = BD + 4096;                // 262,144 + AHT 32,768 (memset once)
  float* AHb  = STATE;                     // 65,536 (2 parities)
  float* ACb  = AHb + 65536;               // 32,768
  float* DHb  = ACb + 32768;               // 65,536 (2 parities)
  float* DCb  = DHb + 65536;               // 32,768
  float* CTXb = DCb + 32768;               // 32,768 (2 parities)
  float* AWb  = CTXb + 32768;              // 16,384
  float* AWSb = AWb + 16384;               // 16,384
  float* AHT  = STATE + 262144;            // 32,768
  float* ENP  = W1T;                       // alias: 131,072 <= 151,552

  hipMemsetAsync(STATE, 0, (size_t)(262144 + 32768) * sizeof(float), stream);

  float* mel = (float*)d_out;
  float* align = mel + (size_t)B_ * TD_ * NM_;

  k_pack_lstm<<<69632, 256, 0, stream>>>(awih, awhh, dwih, dwhh, WAL, WAR, WDL, WDR);
  k_pack_small<<<1135, 256, 0, stream>>>(pw1, pw2, mw, pjw, abih, abhh, dbih, dbhh,
                                         lw, cw, W1T, W2T, MT, PJT, BA, BD, LC);
  k_prenet<<<512, 256, 0, stream>>>(targets, W1T, pb1, W2T, pb2, PN);
  k_penc<<<512, 256, 0, stream>>>(enc, MT, PENC);

  KP kp;
  kp.wal = WAL; kp.war = WAR; kp.wdl = WDL; kp.wdr = WDR;
  kp.pn = PN; kp.penc = PENC;
  kp.qw = qw; kp.ww = www; kp.pjt = PJT; kp.pjb = pjb;
  kp.lc = LC; kp.ba = BA; kp.bd = BD; kp.enc = enc;
  kp.ah = AHb; kp.ac = ACb; kp.dh = DHb; kp.dc = DCb;
  kp.ctx2 = CTXb; kp.aw = AWb; kp.aws = AWSb;
  kp.aht = AHT; kp.enp = ENP; kp.mel = mel; kp.align = align;

  hipFuncSetAttribute((const void*)k_step,
                      hipFuncAttributeMaxDynamicSharedMemorySize, 156416);
  void* kargs[] = { &kp };
  hipLaunchCooperativeKernel((const void*)k_step, dim3(256), dim3(512), kargs,
                             156416, stream);
}

// Round 4
// 187808.191 us; speedup vs baseline: 3.0073x; 3.0073x over previous
//
#include <hip/hip_runtime.h>
#include <hip/hip_fp16.h>
#include <hip/hip_cooperative_groups.h>
#include <cstddef>

namespace cg = cooperative_groups;
typedef unsigned int uint32;

#define B_   32
#define TE_  512
#define TD_  512
#define NM_  80
#define PRE_ 256
#define EH_  512
#define AH_  1024
#define AD_  128

__device__ __forceinline__ float sigf(float x) { return 1.0f / (1.0f + expf(-x)); }

// sum over each 16-lane row via DPP (VALU pipe, no LDS)
__device__ __forceinline__ float rowsum16(float v) {
  int vi;
  vi = __float_as_int(v);
  v += __int_as_float(__builtin_amdgcn_update_dpp(0, vi, 0xB1, 0xF, 0xF, true));  // quad xor1
  vi = __float_as_int(v);
  v += __int_as_float(__builtin_amdgcn_update_dpp(0, vi, 0x4E, 0xF, 0xF, true));  // quad xor2
  vi = __float_as_int(v);
  v += __int_as_float(__builtin_amdgcn_update_dpp(0, vi, 0x124, 0xF, 0xF, true)); // row_ror:4
  vi = __float_as_int(v);
  v += __int_as_float(__builtin_amdgcn_update_dpp(0, vi, 0x128, 0xF, 0xF, true)); // row_ror:8
  return v;
}

// ---------------- prologue: LSTM weight packing (fp16, LDS-resident layouts) ----
// WAL: [blk<128][ks<32][kq<56][16 dw (+4 pad)] dword rd = rows {2rd,2rd+1}, k=kq*32+ks
// WDL: [blk<128][ks<32][kq<70][16 dw (+4 pad)]
// WDT: [blk<128][i<10][ks<32][rg<4][4 dw]  k = 2240+32i+ks, dword rd2 = rows {rg*8+2rd2, +1}
__global__ __launch_bounds__(256) void k_pack_lstm2(
    const float* __restrict__ awih, const float* __restrict__ awhh,
    const float* __restrict__ dwih, const float* __restrict__ dwhh,
    uint32* __restrict__ wal, uint32* __restrict__ wdl, uint32* __restrict__ wdt)
{
  long gid = blockIdx.x * 256L + threadIdx.x;
  const long N1 = 3686400L, N2 = 4603904L, N3 = 655360L;
  if (gid < N1) {
    int blk = (int)(gid / 28800), rem = (int)(gid % 28800);
    int r2 = rem % 900;
    int ks = rem / 900;
    uint32 out = 0;
    if (r2 < 896) {
      int kq = r2 >> 4, rd = r2 & 15;
      int k = kq * 32 + ks;
      int rp0 = blk * 32 + 2 * rd, rp1 = rp0 + 1;
      int row0 = (rp0 & 3) * 1024 + (rp0 >> 2);
      int row1 = (rp1 & 3) * 1024 + (rp1 >> 2);
      float w0 = (k < 768) ? awih[(size_t)row0 * 768 + k] : awhh[(size_t)row0 * 1024 + k - 768];
      float w1 = (k < 768) ? awih[(size_t)row1 * 768 + k] : awhh[(size_t)row1 * 1024 + k - 768];
      __half2 h = __floats2half2_rn(w0, w1);
      out = *(uint32*)&h;
    }
    wal[gid] = out;
  } else if (gid < N1 + N2) {
    long g = gid - N1;
    int blk = (int)(g / 35968), rem = (int)(g % 35968);
    int r2 = rem % 1124;
    int ks = rem / 1124;
    uint32 out = 0;
    if (r2 < 1120) {
      int kq = r2 >> 4, rd = r2 & 15;
      int k = kq * 32 + ks;
      int rp0 = blk * 32 + 2 * rd, rp1 = rp0 + 1;
      int row0 = (rp0 & 3) * 1024 + (rp0 >> 2);
      int row1 = (rp1 & 3) * 1024 + (rp1 >> 2);
      float w0 = (k < 1536) ? dwih[(size_t)row0 * 1536 + k] : dwhh[(size_t)row0 * 1024 + k - 1536];
      float w1 = (k < 1536) ? dwih[(size_t)row1 * 1536 + k] : dwhh[(size_t)row1 * 1024 + k - 1536];
      __half2 h = __floats2half2_rn(w0, w1);
      out = *(uint32*)&h;
    }
    wdl[g] = out;
  } else if (gid < N1 + N2 + N3) {
    long g = gid - N1 - N2;
    int blk = (int)(g / 5120), rem = (int)(g % 5120);
    int rd2 = rem & 3, rg = (rem >> 2) & 3, ks = (rem >> 4) & 31, i = rem >> 9;
    int k = 2240 + 32 * i + ks;
    int r0 = rg * 8 + 2 * rd2;
    int rp0 = blk * 32 + r0, rp1 = rp0 + 1;
    int row0 = (rp0 & 3) * 1024 + (rp0 >> 2);
    int row1 = (rp1 & 3) * 1024 + (rp1 >> 2);
    float w0 = (k < 1536) ? dwih[(size_t)row0 * 1536 + k] : dwhh[(size_t)row0 * 1024 + k - 1536];
    float w1 = (k < 1536) ? dwih[(size_t)row1 * 1536 + k] : dwhh[(size_t)row1 * 1024 + k - 1536];
    __half2 h = __floats2half2_rn(w0, w1);
    wdt[g] = *(uint32*)&h;
  }
}

__global__ __launch_bounds__(256) void k_pack_small(
    const float* __restrict__ w1, const float* __restrict__ w2,
    const float* __restrict__ mw, const float* __restrict__ pw,
    const float* __restrict__ abih, const float* __restrict__ abhh,
    const float* __restrict__ dbih, const float* __restrict__ dbhh,
    const float* __restrict__ lw, const float* __restrict__ cw,
    float* __restrict__ w1t, float* __restrict__ w2t, float* __restrict__ mt,
    float* __restrict__ pjt, float* __restrict__ ba, float* __restrict__ bd,
    float* __restrict__ lc)
{
  int gid = blockIdx.x * 256 + threadIdx.x;
  if (gid < 20480) { int k = gid / 256, j = gid % 256; w1t[gid] = w1[j * 80 + k]; return; }
  gid -= 20480;
  if (gid < 65536) { int k = gid / 256, j = gid % 256; w2t[gid] = w2[j * 256 + k]; return; }
  gid -= 65536;
  if (gid < 65536) { int e = gid / 128, d = gid % 128; mt[gid] = mw[d * 512 + e]; return; }
  gid -= 65536;
  if (gid < 122880) { int k = gid / 80, m = gid % 80; pjt[gid] = pw[m * 1536 + k]; return; }
  gid -= 122880;
  if (gid < 4096) { int j = gid >> 2, g = gid & 3, row = g * 1024 + j; ba[gid] = abih[row] + abhh[row]; return; }
  gid -= 4096;
  if (gid < 4096) { int j = gid >> 2, g = gid & 3, row = g * 1024 + j; bd[gid] = dbih[row] + dbhh[row]; return; }
  gid -= 4096;
  if (gid < 7936) {
    int c = gid / (31 * 128), rem = gid % (31 * 128);
    int kk = rem / 128, d = rem % 128;
    float s = 0.f;
    for (int f = 0; f < 32; ++f) s += lw[d * 32 + f] * cw[(f * 2 + c) * 31 + kk];
    lc[gid] = s;
  }
}

// ---------------- prologue: prenet (verified) ----------------
__global__ __launch_bounds__(256) void k_prenet(
    const float* __restrict__ targets, const float* __restrict__ w1t,
    const float* __restrict__ b1, const float* __restrict__ w2t,
    const float* __restrict__ b2, float* __restrict__ pn)
{
  int t = blockIdx.x, tid = threadIdx.x;
  __shared__ float X[32][80];
  __shared__ float h1[256][33];
  for (int i = tid; i < 2560; i += 256) {
    int b = i / 80, m = i % 80;
    X[b][m] = (t == 0) ? 0.f : targets[((size_t)b * TD_ + (t - 1)) * NM_ + m];
  }
  __syncthreads();
  int j = tid;
  float bj = b1[j];
  for (int bt = 0; bt < 4; ++bt) {
    float acc[8];
#pragma unroll
    for (int i = 0; i < 8; ++i) acc[i] = bj;
    for (int k = 0; k < 80; ++k) {
      float w = w1t[k * 256 + j];
#pragma unroll
      for (int i = 0; i < 8; ++i) acc[i] += w * X[bt * 8 + i][k];
    }
#pragma unroll
    for (int i = 0; i < 8; ++i) h1[j][bt * 8 + i] = fmaxf(acc[i], 0.f);
  }
  __syncthreads();
  float cj = b2[j];
  float* out = pn + (size_t)t * PRE_ * B_;
  for (int bt = 0; bt < 4; ++bt) {
    float acc[8];
#pragma unroll
    for (int i = 0; i < 8; ++i) acc[i] = cj;
    for (int k = 0; k < 256; ++k) {
      float w = w2t[k * 256 + j];
#pragma unroll
      for (int i = 0; i < 8; ++i) acc[i] += w * h1[k][bt * 8 + i];
    }
#pragma unroll
    for (int i = 0; i < 8; ++i) out[j * 32 + bt * 8 + i] = fmaxf(acc[i], 0.f);
  }
}

// ---------------- prologue: processed_enc (verified) ----------------
__global__ __launch_bounds__(256) void k_penc(
    const float* __restrict__ enc, const float* __restrict__ mt,
    float* __restrict__ penc)
{
  int t = blockIdx.x, tid = threadIdx.x;
  __shared__ float encL[32][256];
  __shared__ float red[128][8][2];
  int d = tid & 127, s = tid >> 7;
  float acc[4][8];
#pragma unroll
  for (int bt = 0; bt < 4; ++bt)
#pragma unroll
    for (int i = 0; i < 8; ++i) acc[bt][i] = 0.f;
  for (int eh = 0; eh < 2; ++eh) {
    for (int i = tid; i < 8192; i += 256) {
      int b = i >> 8, e = i & 255;
      encL[b][e] = enc[((size_t)b * TE_ + t) * EH_ + eh * 256 + e];
    }
    __syncthreads();
    for (int bt = 0; bt < 4; ++bt) {
      for (int el = s * 128; el < s * 128 + 128; ++el) {
        float w = mt[(eh * 256 + el) * 128 + d];
#pragma unroll
        for (int i = 0; i < 8; ++i) acc[bt][i] += w * encL[bt * 8 + i][el];
      }
    }
    __syncthreads();
  }
  for (int bt = 0; bt < 4; ++bt) {
#pragma unroll
    for (int i = 0; i < 8; ++i) red[d][i][s] = acc[bt][i];
    __syncthreads();
    if (s == 0) {
#pragma unroll
      for (int i = 0; i < 8; ++i)
        penc[((size_t)t * AD_ + d) * 32 + bt * 8 + i] = red[d][i][0] + red[d][i][1];
    }
    __syncthreads();
  }
}

// ---------------- prologue: enc transpose to fp16 [b][e][t] ----------------
__global__ __launch_bounds__(256) void k_enct(
    const float* __restrict__ enc, __half* __restrict__ enct)
{
  int blk = blockIdx.x, tid = threadIdx.x;
  int b = blk >> 6, t0 = ((blk >> 3) & 7) * 64, e0 = (blk & 7) * 64;
  __shared__ float tile[64][65];
  for (int i = 0; i < 16; ++i) {
    int tl = i * 4 + (tid >> 6), e = tid & 63;
    tile[tl][e] = enc[((size_t)b * TE_ + t0 + tl) * EH_ + e0 + e];
  }
  __syncthreads();
  for (int i = 0; i < 16; ++i) {
    int el = i * 4 + (tid >> 6), tl = tid & 63;
    enct[((size_t)b * EH_ + e0 + el) * TE_ + t0 + tl] = __float2half(tile[tl][el]);
  }
}

// ---------------- persistent step kernel ----------------
struct KP {
  const uint32* wal; const uint32* wdl; const uint4* wdt;
  const float* pn; const float* penc; const __half* enct;
  const float* qw; const float* ww; const float* pjt; const float* pjb;
  const float* lc; const float* ba; const float* bd;
  float* ah; float* ac; float* dh; float* dc; float* ctx2; float* aw; float* aws;
  float* aht; float* enp; float* mel; float* align;
};

template<int T1, int T2>
__device__ __forceinline__ void stage_xc(int c, int nch,
    const float* __restrict__ xp0, const float* __restrict__ xp1,
    const float* __restrict__ xp2, float* __restrict__ XC,
    float4& st, int kidx, int b4)
{
  __syncthreads();
  *(float4*)&XC[kidx * 36 + b4] = st;
  __syncthreads();
  if (c + 1 < nch) {
    int kg = (c + 1) * 64 + kidx;
    const float* src = (kg < T1) ? xp0 + (size_t)kg * 32
                     : (kg < T2) ? xp1 + (size_t)(kg - T1) * 32
                                 : xp2 + (size_t)(kg - T2) * 32;
    st = *(const float4*)(src + b4);
  }
}

__device__ __forceinline__ void fma2(uint4 wv, const float* __restrict__ XC,
                                     int xb, float* acc)
{
  const __half2* hp = (const __half2*)&wv;
  float w[8];
#pragma unroll
  for (int d = 0; d < 4; ++d) {
    float2 f = __half22float2(hp[d]);
    w[2 * d] = f.x; w[2 * d + 1] = f.y;
  }
  float4 xa = *(const float4*)&XC[xb];
  float4 xc2 = *(const float4*)&XC[xb + 4];
  float x[8] = {xa.x, xa.y, xa.z, xa.w, xc2.x, xc2.y, xc2.z, xc2.w};
#pragma unroll
  for (int ri = 0; ri < 8; ++ri)
#pragma unroll
    for (int bi = 0; bi < 8; ++bi)
      acc[ri * 8 + bi] = fmaf(w[ri], x[bi], acc[ri * 8 + bi]);
}

__device__ __forceinline__ void lstm_finish(
    float* acc, float* __restrict__ GT, const float* __restrict__ bias,
    float* __restrict__ cst, float* __restrict__ hout, float* __restrict__ aht,
    int rp0, int tid, int ks, int bq, int rg)
{
#pragma unroll
  for (int i = 0; i < 64; ++i) {
    float v = rowsum16(acc[i]);
    acc[i] = v + __shfl_xor(v, 16);
  }
  if (ks == 0) {
#pragma unroll
    for (int ri = 0; ri < 8; ++ri) {
      *(float4*)&GT[(rg * 8 + ri) * 32 + bq * 8] =
          make_float4(acc[ri * 8 + 0], acc[ri * 8 + 1], acc[ri * 8 + 2], acc[ri * 8 + 3]);
      *(float4*)&GT[(rg * 8 + ri) * 32 + bq * 8 + 4] =
          make_float4(acc[ri * 8 + 4], acc[ri * 8 + 5], acc[ri * 8 + 6], acc[ri * 8 + 7]);
    }
  }
  __syncthreads();
  if (tid < 256) {
    int jl = tid >> 5, b = tid & 31;
    float gi = GT[(jl * 4 + 0) * 32 + b] + bias[rp0 + jl * 4 + 0];
    float gf = GT[(jl * 4 + 1) * 32 + b] + bias[rp0 + jl * 4 + 1];
    float gg = GT[(jl * 4 + 2) * 32 + b] + bias[rp0 + jl * 4 + 2];
    float go = GT[(jl * 4 + 3) * 32 + b] + bias[rp0 + jl * 4 + 3];
    int j = (rp0 >> 2) + jl;
    float c0 = cst[j * 32 + b];
    float c2 = sigf(gf) * c0 + sigf(gi) * tanhf(gg);
    float h2 = sigf(go) * tanhf(c2);
    cst[j * 32 + b] = c2;
    hout[j * 32 + b] = h2;
    if (aht) aht[(size_t)b * 1024 + j] = h2;
  }
}

__device__ __forceinline__ void run_lstm_a(const KP& p, int t, int pp, int pc,
    uint32* WlU, float* XC, float* GT, int tid, int ks, int bq, int rg,
    int kidx, int b4, int blk)
{
  float acc[64];
#pragma unroll
  for (int i = 0; i < 64; ++i) acc[i] = 0.f;
  const float* xp0 = p.pn + (size_t)t * 8192;
  const float* xp1 = p.ctx2 + pp * 16384;
  const float* xp2 = p.ah + pp * 32768;
  float4 st;
  {
    int kg = kidx;
    const float* src = (kg < 256) ? xp0 + (size_t)kg * 32
                     : (kg < 768) ? xp1 + (size_t)(kg - 256) * 32
                                  : xp2 + (size_t)(kg - 768) * 32;
    st = *(const float4*)(src + b4);
  }
  const int wb = ks * 900 + rg * 4;
  const int xr = ks * 36 + bq * 8;
  for (int c = 0; c < 28; ++c) {
    stage_xc<256, 768>(c, 28, xp0, xp1, xp2, XC, st, kidx, b4);
    fma2(*(const uint4*)&WlU[wb + (2 * c) * 16], XC, xr, acc);
    fma2(*(const uint4*)&WlU[wb + (2 * c + 1) * 16], XC, xr + 32 * 36, acc);
  }
  lstm_finish(acc, GT, p.ba, p.ac, p.ah + pc * 32768, p.aht, blk * 32, tid, ks, bq, rg);
}

__device__ __forceinline__ void run_lstm_d(const KP& p,
    const float* xp0, const float* xp1, const float* xp2, float* dh_w,
    uint32* WlU, float* XC, float* GT, const uint4* wt,
    int tid, int ks, int bq, int rg, int kidx, int b4, int blk)
{
  float acc[64];
#pragma unroll
  for (int i = 0; i < 64; ++i) acc[i] = 0.f;
  float4 st;
  st = *(const float4*)(xp0 + (size_t)kidx * 32 + b4);  // chunk 0 all in xp0 (1024 wide)
  const int wb = ks * 1124 + rg * 4;
  const int xr = ks * 36 + bq * 8;
  for (int c = 0; c < 35; ++c) {
    stage_xc<1024, 1536>(c, 40, xp0, xp1, xp2, XC, st, kidx, b4);
    fma2(*(const uint4*)&WlU[wb + (2 * c) * 16], XC, xr, acc);
    fma2(*(const uint4*)&WlU[wb + (2 * c + 1) * 16], XC, xr + 32 * 36, acc);
  }
#pragma unroll
  for (int c2 = 0; c2 < 5; ++c2) {
    stage_xc<1024, 1536>(35 + c2, 40, xp0, xp1, xp2, XC, st, kidx, b4);
    fma2(wt[c2 * 2], XC, xr, acc);
    fma2(wt[c2 * 2 + 1], XC, xr + 32 * 36, acc);
  }
  lstm_finish(acc, GT, p.bd, p.dc, dh_w, nullptr, (blk - 128) * 32, tid, ks, bq, rg);
}

__device__ __forceinline__ void mel_block(
    const float* __restrict__ dhp, const float* __restrict__ ctp,
    const float* __restrict__ pjt, const float* __restrict__ pjb,
    float* __restrict__ mel, int bb, int tt, float* S, int tid)
{
  float* xo = S + 1536;
  float* ro = S + 3072;
  for (int i = tid; i < 1536; i += 512)
    xo[i] = (i < 1024) ? dhp[i * 32 + bb] : ctp[(i - 1024) * 32 + bb];
  __syncthreads();
  if (tid < 480) {
    int m = tid % 80, k2 = tid / 80;
    float a2 = 0.f;
    for (int k = k2 * 256; k < k2 * 256 + 256; ++k) a2 += pjt[k * 80 + m] * xo[k];
    ro[m * 8 + k2] = a2;
  }
  __syncthreads();
  if (tid < 80) {
    float s3 = pjb[tid];
#pragma unroll
    for (int k = 0; k < 6; ++k) s3 += ro[tid * 8 + k];
    mel[((size_t)bb * TD_ + tt) * NM_ + tid] = s3;
  }
}

__global__ __launch_bounds__(512) void k_step(KP p)
{
  cg::grid_group grid = cg::this_grid();
  extern __shared__ float LDSF[];
  const int blk = blockIdx.x, tid = threadIdx.x;
  const int ks = tid & 31, bq = (tid >> 5) & 3, rg = tid >> 7;
  const int kidx = tid >> 3, b4 = (tid & 7) * 4;
  const bool isA = blk < 128;
  float* SC = LDSF + (isA ? 28800 : 35968);
  float* XC = SC;
  float* GT = SC + 2304;
  uint32* WlU = (uint32*)LDSF;

  // one-time: weights into LDS (+VGPR tail for D)
  {
    const uint32* src = isA ? p.wal + (size_t)blk * 28800
                            : p.wdl + (size_t)(blk - 128) * 35968;
    int n4 = isA ? 7200 : 8992;
    for (int i = tid; i < n4; i += 512)
      ((uint4*)WlU)[i] = ((const uint4*)src)[i];
  }
  uint4 wt[10];
  if (!isA) {
#pragma unroll
    for (int i = 0; i < 10; ++i)
      wt[i] = p.wdt[(size_t)(blk - 128) * 1280 + (i * 32 + ks) * 4 + rg];
  }
  __syncthreads();

  for (int t = 0; t < TD_; ++t) {
    const int pc = t & 1, pp = pc ^ 1;
    // ---- PA: lstm_a(t) [0..127] || lstm_d(t-1) [128..255] ----
    if (isA) {
      run_lstm_a(p, t, pp, pc, WlU, XC, GT, tid, ks, bq, rg, kidx, b4, blk);
    } else if (t > 0) {
      run_lstm_d(p, p.ah + pp * 32768, p.ctx2 + pp * 16384, p.dh + pc * 32768,
                 p.dh + pp * 32768, WlU, XC, GT, wt, tid, ks, bq, rg, kidx, b4, blk);
    }
    grid.sync();
    // ---- PB: q-slice + location conv + energies partials ----
    {
      int tc = blk >> 3, ds = blk & 7;
      int t0 = tc * 16, d0 = ds * 16;
      float* win = SC;
      float* lcs = SC + 2944;
      float* qs  = SC + 3936;
      float* wws = SC + 4448;
      for (int i = tid; i < 2944; i += 512) {
        int c = i / 1472, r = (i >> 5) % 46, bb = i & 31;
        int tg = t0 - 15 + r;
        float v = 0.f;
        if (tg >= 0 && tg < 512) v = (c ? p.aws : p.aw)[tg * 32 + bb];
        win[i] = v;
      }
      for (int i = tid; i < 992; i += 512) {
        int c = i / 496, kk = (i >> 4) % 31, dl = i & 15;
        lcs[i] = p.lc[(c * 31 + kk) * 128 + d0 + dl];
      }
      if (tid < 16) wws[tid] = p.ww[d0 + tid];
      {
        int dl = tid & 15, bb = tid >> 4;
        const float* qrow = p.qw + (size_t)(d0 + dl) * 1024;
        const float* arow = p.aht + (size_t)bb * 1024;
        float acc = 0.f;
#pragma unroll 4
        for (int k = 0; k < 1024; k += 4) {
          float4 qv = *(const float4*)(qrow + k);
          float4 av = *(const float4*)(arow + k);
          acc += qv.x * av.x + qv.y * av.y + qv.z * av.z + qv.w * av.w;
        }
        qs[dl * 32 + bb] = acc;
      }
      __syncthreads();
      {
        int bb = tid & 31, th = tid >> 5;
        int tt = t0 + th;
        float pa[16];
#pragma unroll
        for (int i = 0; i < 16; ++i) pa[i] = 0.f;
        for (int c = 0; c < 2; ++c) {
          for (int kk = 0; kk < 31; ++kk) {
            float wv = win[c * 1472 + (th + kk) * 32 + bb];
            const float4* lr = (const float4*)(lcs + c * 496 + kk * 16);
            float4 l0 = lr[0], l1 = lr[1], l2 = lr[2], l3 = lr[3];
            pa[0]  += l0.x * wv; pa[1]  += l0.y * wv; pa[2]  += l0.z * wv; pa[3]  += l0.w * wv;
            pa[4]  += l1.x * wv; pa[5]  += l1.y * wv; pa[6]  += l1.z * wv; pa[7]  += l1.w * wv;
            pa[8]  += l2.x * wv; pa[9]  += l2.y * wv; pa[10] += l2.z * wv; pa[11] += l2.w * wv;
            pa[12] += l3.x * wv; pa[13] += l3.y * wv; pa[14] += l3.z * wv; pa[15] += l3.w * wv;
          }
        }
        float ep = 0.f;
#pragma unroll
        for (int dl = 0; dl < 16; ++dl) {
          float v = qs[dl * 32 + bb] + p.penc[((size_t)tt * 128 + d0 + dl) * 32 + bb] + pa[dl];
          ep += wws[dl] * tanhf(v);
        }
        p.enp[(size_t)bb * 4096 + tt * 8 + ds] = ep;
      }
    }
    grid.sync();
    // ---- PC: softmax + ctx (+aw/aws/align, +mel(t-1)) ----
    {
      int bb = blk >> 3, et = blk & 7;
      float* Sr  = SC;
      float* awL = SC + 512;
      float* cr  = SC + 1024;
      const float4* ep4 = (const float4*)(p.enp + (size_t)bb * 4096 + tid * 8);
      float4 u0 = ep4[0], u1 = ep4[1];
      float e = u0.x + u0.y + u0.z + u0.w + u1.x + u1.y + u1.z + u1.w;
      Sr[tid] = e; __syncthreads();
      for (int off = 256; off; off >>= 1) {
        if (tid < off) Sr[tid] = fmaxf(Sr[tid], Sr[tid + off]);
        __syncthreads();
      }
      float mx = Sr[0]; __syncthreads();
      float x = expf(e - mx);
      Sr[tid] = x; __syncthreads();
      for (int off = 256; off; off >>= 1) {
        if (tid < off) Sr[tid] += Sr[tid + off];
        __syncthreads();
      }
      float a = x * (1.f / Sr[0]);
      awL[tid] = a;
      __syncthreads();
      int el = tid & 63, ts = tid >> 6;
      const __half2* eb = (const __half2*)(p.enct +
          ((size_t)(bb * 512 + et * 64 + el)) * 512 + ts * 64);
      float acc = 0.f;
#pragma unroll 8
      for (int i = 0; i < 32; ++i) {
        float2 f = __half22float2(eb[i]);
        acc += awL[ts * 64 + 2 * i] * f.x + awL[ts * 64 + 2 * i + 1] * f.y;
      }
      cr[ts * 64 + el] = acc;
      __syncthreads();
      if (tid < 64) {
        float s2 = 0.f;
#pragma unroll
        for (int k = 0; k < 8; ++k) s2 += cr[k * 64 + tid];
        p.ctx2[pc * 16384 + (et * 64 + tid) * 32 + bb] = s2;
      }
      if (et == 0) {
        p.aw[tid * 32 + bb] = a;
        p.aws[tid * 32 + bb] += a;
        p.align[((size_t)bb * TD_ + t) * TE_ + tid] = a;
      }
      if (et == 1 && t > 0) {
        mel_block(p.dh + pp * 32768, p.ctx2 + pp * 16384, p.pjt, p.pjb,
                  p.mel, bb, t - 1, SC, tid);
      }
    }
    grid.sync();
  }
  // ---- epilogue: lstm_d(511) then mel(511). t=512 -> pc=0, pp=1 ----
  if (!isA) {
    run_lstm_d(p, p.ah + 32768, p.ctx2 + 16384, p.dh + 0,
               p.dh + 32768, WlU, XC, GT, wt, tid, ks, bq, rg, kidx, b4, blk);
  }
  grid.sync();
  if (blk < 32) {
    mel_block(p.dh + 32768, p.ctx2 + 16384, p.pjt, p.pjb, p.mel, blk, 511, SC, tid);
  }
}

extern "C" void kernel_launch(void* const* d_in, const int* in_sizes, int n_in,
                              void* d_out, int out_size, void* d_ws, size_t ws_size,
                              hipStream_t stream)
{
  const float* enc     = (const float*)d_in[0];
  const float* targets = (const float*)d_in[1];
  const float* pw1  = (const float*)d_in[2];
  const float* pb1  = (const float*)d_in[3];
  const float* pw2  = (const float*)d_in[4];
  const float* pb2  = (const float*)d_in[5];
  const float* mw   = (const float*)d_in[6];
  const float* qw   = (const float*)d_in[7];
  const float* www  = (const float*)d_in[8];
  const float* lw   = (const float*)d_in[9];
  const float* cw   = (const float*)d_in[10];
  const float* awih = (const float*)d_in[11];
  const float* awhh = (const float*)d_in[12];
  const float* abih = (const float*)d_in[13];
  const float* abhh = (const float*)d_in[14];
  const float* dwih = (const float*)d_in[15];
  const float* dwhh = (const float*)d_in[16];
  const float* dbih = (const float*)d_in[17];
  const float* dbhh = (const float*)d_in[18];
  const float* pjw  = (const float*)d_in[19];
  const float* pjb  = (const float*)d_in[20];

  uint32* wsb = (uint32*)d_ws;
  uint32* WAL2 = wsb;                      // 3,686,400 dw
  uint32* WDL2 = WAL2 + 3686400;           // 4,603,904 dw
  uint32* WDT  = WDL2 + 4603904;           // 655,360 dw (16B aligned)
  __half* ENCT = (__half*)(WDT + 655360);  // 8,388,608 halfs = 4,194,304 dw
  float*  PN   = (float*)(WDT + 655360 + 4194304);  // 4,194,304
  float*  PENC = PN + 4194304;             // 2,097,152
  float*  W1T  = PENC + 2097152;           // 20,480  (ENP aliases W1T..)
  float*  W2T  = W1T + 20480;              // 65,536
  float*  MT   = W2T + 65536;              // 65,536
  float*  PJT  = MT + 65536;               // 122,880
  float*  LC   = PJT + 122880;             // 7,936
  float*  BA   = LC + 7936;                // 4,096
  float*  BD   = BA + 4096;                // 4,096
  float*  STATE = BD + 4096;               // 262,144 + AHT 32,768
  float*  AHb  = STATE;                    // 65,536 (2 parities)
  float*  ACb  = AHb + 65536;              // 32,768
  float*  DHb  = ACb + 32768;              // 65,536 (2 parities)
  float*  DCb  = DHb + 65536;              // 32,768
  float*  CTXb = DCb + 32768;              // 32,768 (2 parities)
  float*  AWb  = CTXb + 32768;             // 16,384
  float*  AWSb = AWb + 16384;              // 16,384
  float*  AHT  = STATE + 262144;           // 32,768
  float*  ENP  = W1T;                      // alias 131,072 <= 151,552

  hipMemsetAsync(STATE, 0, (size_t)(262144 + 32768) * sizeof(float), stream);

  float* mel = (float*)d_out;
  float* align = mel + (size_t)B_ * TD_ * NM_;

  k_pack_lstm2<<<34944, 256, 0, stream>>>(awih, awhh, dwih, dwhh, WAL2, WDL2, WDT);
  k_pack_small<<<1135, 256, 0, stream>>>(pw1, pw2, mw, pjw, abih, abhh, dbih, dbhh,
                                         lw, cw, W1T, W2T, MT, PJT, BA, BD, LC);
  k_prenet<<<512, 256, 0, stream>>>(targets, W1T, pb1, W2T, pb2, PN);
  k_penc<<<512, 256, 0, stream>>>(enc, MT, PENC);
  k_enct<<<2048, 256, 0, stream>>>(enc, ENCT);

  KP kp;
  kp.wal = WAL2; kp.wdl = WDL2; kp.wdt = (const uint4*)WDT;
  kp.pn = PN; kp.penc = PENC; kp.enct = ENCT;
  kp.qw = qw; kp.ww = www; kp.pjt = PJT; kp.pjb = pjb;
  kp.lc = LC; kp.ba = BA; kp.bd = BD;
  kp.ah = AHb; kp.ac = ACb; kp.dh = DHb; kp.dc = DCb;
  kp.ctx2 = CTXb; kp.aw = AWb; kp.aws = AWSb;
  kp.aht = AHT; kp.enp = ENP; kp.mel = mel; kp.align = align;

  hipFuncSetAttribute((const void*)k_step,
                      hipFuncAttributeMaxDynamicSharedMemorySize, 161728);
  void* kargs[] = { &kp };
  hipLaunchCooperativeKernel((const void*)k_step, dim3(256), dim3(512), kargs,
                             161728, stream);
}